// Round 8
// baseline (111.693 us; speedup 1.0000x reference)
//
#include <hip/hip_runtime.h>

// GAT dense attention. MFMA everywhere; softmax numerator factorized rank-1:
//   p_ij = exp2(max(A_i+U_j, C_i+V_j)) = max(alpha_i*E_j, beta_i*F_j)
// all factors in (0,1] -> packed-f16 inner loop, no exp, den via ones-MFMA.
// Shapes: B=4, N=2048, F_in=128, H=4, d=32. out[b][n][h*32+d] fp32.

#define LOG2E 1.4426950408889634f
constexpr int Nn = 2048, Fin = 128, Dd = 32;

typedef _Float16 half8 __attribute__((ext_vector_type(8)));
typedef _Float16 half4v __attribute__((ext_vector_type(4)));
typedef _Float16 half2v __attribute__((ext_vector_type(2)));
typedef float f32x4 __attribute__((ext_vector_type(4)));

union H8 { half2v h2[4]; half8 h8; };

// ---------------- Kernel 1: Wh = x @ W (f16 hi/lo MFMA), s, t, whT ----------
// 512 blocks (16 bh x 32 tiles of 64 rows) x 256 thr; wave = one 16-row M-tile.
// W staged in padded LDS (<=2-way bank aliasing = free). 3-product split keeps
// Wh fp32-exact. Stores whT f16 [bh][d][j] + s,t.
__global__ __launch_bounds__(256) void k1_wh(
    const float* __restrict__ x, const float* __restrict__ W,
    const float* __restrict__ a, _Float16* __restrict__ whT,
    float* __restrict__ sArr, float* __restrict__ tArr) {
  __shared__ float Wlds[Fin][Dd + 1];        // 128x33
  int blk = blockIdx.x;
  int bh = blk >> 5, tile = blk & 31;
  int b = bh >> 2, h = bh & 3;
  int tid = threadIdx.x, w = tid >> 6, lane = tid & 63;
  int q = lane >> 4, m = lane & 15;
  int rowbase = tile * 64 + w * 16;

  {  // stage W[h]: 4096 floats, 4 float4/thread coalesced, scalar LDS writes
    const float4* src = (const float4*)(W + h * Fin * Dd);
#pragma unroll
    for (int r = 0; r < 4; ++r) {
      float4 v = src[tid + r * 256];
      int e = (tid + r * 256) * 4;
      Wlds[e >> 5][e & 31] = v.x;
      Wlds[(e + 1) >> 5][(e + 1) & 31] = v.y;
      Wlds[(e + 2) >> 5][(e + 2) & 31] = v.z;
      Wlds[(e + 3) >> 5][(e + 3) & 31] = v.w;
    }
  }
  const float* xb = x + (size_t)(b * Nn + rowbase + m) * Fin;
  float4 xl[8];
#pragma unroll
  for (int kt = 0; kt < 4; ++kt) {           // hoisted, overlaps LDS stage
    xl[2 * kt] = *(const float4*)(xb + kt * 32 + q * 8);
    xl[2 * kt + 1] = *(const float4*)(xb + kt * 32 + q * 8 + 4);
  }
  __syncthreads();

  f32x4 acc[2];
  acc[0] = (f32x4){0.f, 0.f, 0.f, 0.f};
  acc[1] = (f32x4){0.f, 0.f, 0.f, 0.f};

#pragma unroll
  for (int kt = 0; kt < 4; ++kt) {
    float xv[8] = {xl[2 * kt].x, xl[2 * kt].y, xl[2 * kt].z, xl[2 * kt].w,
                   xl[2 * kt + 1].x, xl[2 * kt + 1].y, xl[2 * kt + 1].z, xl[2 * kt + 1].w};
    half8 Ah, Al;
#pragma unroll
    for (int j = 0; j < 8; ++j) {
      _Float16 hi = (_Float16)xv[j];
      Ah[j] = hi;
      Al[j] = (_Float16)(xv[j] - (float)hi);
    }
#pragma unroll
    for (int nt = 0; nt < 2; ++nt) {
      half8 Bh, Bl;
#pragma unroll
      for (int j = 0; j < 8; ++j) {
        float wv = Wlds[kt * 32 + q * 8 + j][nt * 16 + m];  // <=2-way, free
        _Float16 hi = (_Float16)wv;
        Bh[j] = hi;
        Bl[j] = (_Float16)(wv - (float)hi);
      }
      acc[nt] = __builtin_amdgcn_mfma_f32_16x16x32_f16(Ah, Bh, acc[nt], 0, 0, 0);
      acc[nt] = __builtin_amdgcn_mfma_f32_16x16x32_f16(Al, Bh, acc[nt], 0, 0, 0);
      acc[nt] = __builtin_amdgcn_mfma_f32_16x16x32_f16(Ah, Bl, acc[nt], 0, 0, 0);
    }
  }

  // C layout: lane(q,m) -> rows rowbase+q*4+r, col d = nt*16+m.
#pragma unroll
  for (int nt = 0; nt < 2; ++nt) {
    int d = nt * 16 + m;
    half4v h4;
#pragma unroll
    for (int r = 0; r < 4; ++r) h4[r] = (_Float16)acc[nt][r];
    *(half4v*)(whT + (size_t)(bh * Dd + d) * Nn + rowbase + q * 4) = h4;
  }

  const float* ah = a + h * 2 * Dd;
  float a1m0 = ah[m], a1m1 = ah[16 + m];
  float a2m0 = ah[Dd + m], a2m1 = ah[Dd + 16 + m];
#pragma unroll
  for (int r = 0; r < 4; ++r) {
    float ps = acc[0][r] * a1m0 + acc[1][r] * a1m1;
    float pt = acc[0][r] * a2m0 + acc[1][r] * a2m1;
#pragma unroll
    for (int off = 1; off < 16; off <<= 1) {
      ps += __shfl_xor(ps, off);
      pt += __shfl_xor(pt, off);
    }
    if (m == 0) {
      sArr[bh * Nn + rowbase + q * 4 + r] = ps;
      tArr[bh * Nn + rowbase + q * 4 + r] = pt;
    }
  }
}

// ---------------- Kernel 3: h = softmax(e) @ Wh via f16 MFMA ----------------
// 512 blocks (16 bh x 32 tiles of 64 rows) x 256 thr = 4 waves (j-quarters).
// Wave handles 4 M-tiles per B-load pair (12 MFMA / 2 loads), 2-step register
// prefetch, den via ones-MFMA, 4-wave LDS reduce. 34.8 KB LDS -> 4 blocks/CU.
__global__ __launch_bounds__(256) void k3_attn(
    const _Float16* __restrict__ whT, const float* __restrict__ sArr,
    const float* __restrict__ tArr, float* __restrict__ out) {
  __shared__ float smem[4 * 64 * 33 + 256];  // 34.8 KB union
  _Float16* Ef = (_Float16*)smem;            // [2048] f16
  _Float16* Ff = (_Float16*)(smem + 1024);   // [2048] f16
  float* red = smem + 2048;                  // [256] block-max scratch

  int blk = blockIdx.x;
  int bh = blk >> 5, tile = blk & 31;
  int b = bh >> 2, h = bh & 3;
  int tid = threadIdx.x, w = tid >> 6, lane = tid & 63;
  int q = lane >> 4, m = lane & 15;

  // ---- prologue: T, then E_j = 2^(L(t-T)), F_j = 2^(0.2L(t-T)) ----
  float tv[8];
  float mx = -1e30f;
#pragma unroll
  for (int k = 0; k < 8; ++k) {
    tv[k] = tArr[bh * Nn + tid + k * 256];
    mx = fmaxf(mx, tv[k]);
  }
  red[tid] = mx;
  __syncthreads();
  for (int ss = 128; ss > 0; ss >>= 1) {
    if (tid < ss) red[tid] = fmaxf(red[tid], red[tid + ss]);
    __syncthreads();
  }
  float T = red[0];
#pragma unroll
  for (int k = 0; k < 8; ++k) {
    float dt = tv[k] - T;                    // <= 0
    Ef[tid + k * 256] = (_Float16)__builtin_amdgcn_exp2f(LOG2E * dt);
    Ff[tid + k * 256] = (_Float16)__builtin_amdgcn_exp2f(0.2f * LOG2E * dt);
  }
  half2v aa[4], bb[4];
#pragma unroll
  for (int t = 0; t < 4; ++t) {
    float es = sArr[bh * Nn + tile * 64 + t * 16 + m] + T;
    float al = __builtin_amdgcn_exp2f(0.8f * LOG2E * fminf(es, 0.f));
    float be = __builtin_amdgcn_exp2f(-0.8f * LOG2E * fmaxf(es, 0.f));
    aa[t] = (half2v){(_Float16)al, (_Float16)al};
    bb[t] = (half2v){(_Float16)be, (_Float16)be};
  }
  __syncthreads();                           // E/F visible to all waves

  f32x4 acc[4][2], accD[4];
#pragma unroll
  for (int t = 0; t < 4; ++t) {
    acc[t][0] = (f32x4){0.f, 0.f, 0.f, 0.f};
    acc[t][1] = (f32x4){0.f, 0.f, 0.f, 0.f};
    accD[t] = (f32x4){0.f, 0.f, 0.f, 0.f};
  }
  const _Float16 one = (_Float16)1.f;
  const half8 ONES = (half8){one, one, one, one, one, one, one, one};

  const _Float16* r0 = whT + (size_t)(bh * Dd + m) * Nn;
  const _Float16* r1 = whT + (size_t)(bh * Dd + 16 + m) * Nn;
  int jw = w * 512 + q * 8;                  // wave's j-window base (+q offset)

  // 2-step-deep register prefetch (tail over-read lands in slack ws: unused)
  half8 pB0[2], pB1[2];
  pB0[0] = *(const half8*)(r0 + jw);
  pB1[0] = *(const half8*)(r1 + jw);
  pB0[1] = *(const half8*)(r0 + jw + 32);
  pB1[1] = *(const half8*)(r1 + jw + 32);

  for (int s = 0; s < 16; ++s) {
    half8 B0 = pB0[s & 1], B1 = pB1[s & 1];
    int jn = jw + (s + 2) * 32;
    pB0[s & 1] = *(const half8*)(r0 + jn);
    pB1[s & 1] = *(const half8*)(r1 + jn);
    H8 E, F;
    E.h8 = *(const half8*)&Ef[w * 512 + s * 32 + q * 8];
    F.h8 = *(const half8*)&Ff[w * 512 + s * 32 + q * 8];
#pragma unroll
    for (int t = 0; t < 4; ++t) {
      H8 P;
#pragma unroll
      for (int kk = 0; kk < 4; ++kk)
        P.h2[kk] = __builtin_elementwise_max(aa[t] * E.h2[kk], bb[t] * F.h2[kk]);
      acc[t][0] = __builtin_amdgcn_mfma_f32_16x16x32_f16(P.h8, B0, acc[t][0], 0, 0, 0);
      acc[t][1] = __builtin_amdgcn_mfma_f32_16x16x32_f16(P.h8, B1, acc[t][1], 0, 0, 0);
      accD[t] = __builtin_amdgcn_mfma_f32_16x16x32_f16(P.h8, ONES, accD[t], 0, 0, 0);
    }
  }

  // ---- epilogue: 4-wave LDS reduce + divide + elu + coalesced store ----
  __syncthreads();                           // E/F dead; reuse smem
  float* redN = smem;                        // [4][64][33]
  float* redD = smem + 4 * 64 * 33;          // [4][64]
#pragma unroll
  for (int t = 0; t < 4; ++t) {
#pragma unroll
    for (int dh = 0; dh < 2; ++dh)
#pragma unroll
      for (int r = 0; r < 4; ++r)
        redN[(w * 64 + t * 16 + q * 4 + r) * 33 + dh * 16 + m] = acc[t][dh][r];
    if (m == 0)
#pragma unroll
      for (int r = 0; r < 4; ++r) redD[w * 64 + t * 16 + q * 4 + r] = accD[t][r];
  }
  __syncthreads();
  {
    int rl = tid >> 2, dg = (tid & 3) * 8;   // row, 8-col group
    float num[8];
    float dt = 0.f;
#pragma unroll
    for (int i = 0; i < 8; ++i) num[i] = 0.f;
#pragma unroll
    for (int ww = 0; ww < 4; ++ww) {
      dt += redD[ww * 64 + rl];
#pragma unroll
      for (int i = 0; i < 8; ++i) num[i] += redN[(ww * 64 + rl) * 33 + dg + i];
    }
    float rd = 1.0f / dt;                    // den >= ~1 by construction
    float* orow = out + (size_t)(b * Nn + tile * 64 + rl) * (4 * Dd) + h * Dd + dg;
#pragma unroll
    for (int i = 0; i < 8; ++i) {
      float hv = num[i] * rd;
      num[i] = hv > 0.f ? hv : (__builtin_amdgcn_exp2f(hv * LOG2E) - 1.0f);
    }
    *(float4*)orow = make_float4(num[0], num[1], num[2], num[3]);
    *((float4*)orow + 1) = make_float4(num[4], num[5], num[6], num[7]);
  }
}

extern "C" void kernel_launch(void* const* d_in, const int* in_sizes, int n_in,
                              void* d_out, int out_size, void* d_ws, size_t ws_size,
                              hipStream_t stream) {
  const float* x = (const float*)d_in[0];   // (4,2048,128)
  const float* W = (const float*)d_in[1];   // (4,128,32)
  const float* a = (const float*)d_in[2];   // (4,64)
  float* out = (float*)d_out;               // (4,2048,128)

  float* wsf = (float*)d_ws;
  float* sArr = wsf;                        // 32768 f32
  float* tArr = sArr + 32768;               // 32768 f32
  _Float16* whT = (_Float16*)(tArr + 32768);  // 16*32*2048 f16 = 2 MB
  // (ws has ~264 MB slack after whT; k3's prefetch tail over-read lands there)

  k1_wh<<<dim3(512), dim3(256), 0, stream>>>(x, W, a, whT, sArr, tArr);
  k3_attn<<<dim3(512), dim3(256), 0, stream>>>(whT, sArr, tArr, out);
}

// Round 9
// 77.661 us; speedup vs baseline: 1.4382x; 1.4382x over previous
//
#include <hip/hip_runtime.h>

// GAT dense attention. MFMA everywhere; softmax numerator factorized rank-1:
//   p_ij = exp2(max(A_i+U_j, C_i+V_j)) = max(alpha_i*E_j, beta_i*F_j)
// all factors in (0,1] -> packed-f16 inner loop, no exp in the hot loop.
// REVERT to the R5-measured-best configuration (77.1 us): no manual prefetch,
// fdot2 denominator, 4-wave j-split. Manual pipelining variants (R6/R8)
// regressed 25-45% -- compiler's schedule of this loop is better.
// Shapes: B=4, N=2048, F_in=128, H=4, d=32. out[b][n][h*32+d] fp32.

#define LOG2E 1.4426950408889634f
constexpr int Nn = 2048, Fin = 128, Dd = 32;

typedef _Float16 half8 __attribute__((ext_vector_type(8)));
typedef _Float16 half4v __attribute__((ext_vector_type(4)));
typedef _Float16 half2v __attribute__((ext_vector_type(2)));
typedef float f32x4 __attribute__((ext_vector_type(4)));

union H8 { half2v h2[4]; half8 h8; };

// ---------------- Kernel 1: Wh = x @ W (f16 hi/lo MFMA), s, t, whT ----------
// 512 blocks (16 bh x 32 tiles of 64 rows) x 256 thr; wave = one 16-row M-tile.
// 3-product split keeps Wh fp32-exact. Stores whT f16 [bh][d][j] + s,t.
__global__ __launch_bounds__(256) void k1_wh(
    const float* __restrict__ x, const float* __restrict__ W,
    const float* __restrict__ a, _Float16* __restrict__ whT,
    float* __restrict__ sArr, float* __restrict__ tArr) {
  int blk = blockIdx.x;
  int bh = blk >> 5, tile = blk & 31;
  int b = bh >> 2, h = bh & 3;
  int tid = threadIdx.x, w = tid >> 6, lane = tid & 63;
  int q = lane >> 4, m = lane & 15;
  int rowbase = tile * 64 + w * 16;

  const float* Wq = W + h * Fin * Dd;
  const float* xb = x + (size_t)(b * Nn + rowbase + m) * Fin;

  f32x4 acc[2];
  acc[0] = (f32x4){0.f, 0.f, 0.f, 0.f};
  acc[1] = (f32x4){0.f, 0.f, 0.f, 0.f};

#pragma unroll
  for (int kt = 0; kt < 4; ++kt) {
    float4 x0 = *(const float4*)(xb + kt * 32 + q * 8);
    float4 x1 = *(const float4*)(xb + kt * 32 + q * 8 + 4);
    float xv[8] = {x0.x, x0.y, x0.z, x0.w, x1.x, x1.y, x1.z, x1.w};
    half8 Ah, Al;
#pragma unroll
    for (int j = 0; j < 8; ++j) {
      _Float16 hi = (_Float16)xv[j];
      Ah[j] = hi;
      Al[j] = (_Float16)(xv[j] - (float)hi);
    }
#pragma unroll
    for (int nt = 0; nt < 2; ++nt) {
      half8 Bh, Bl;
#pragma unroll
      for (int j = 0; j < 8; ++j) {
        float wv = Wq[(kt * 32 + q * 8 + j) * Dd + nt * 16 + m];
        _Float16 hi = (_Float16)wv;
        Bh[j] = hi;
        Bl[j] = (_Float16)(wv - (float)hi);
      }
      acc[nt] = __builtin_amdgcn_mfma_f32_16x16x32_f16(Ah, Bh, acc[nt], 0, 0, 0);
      acc[nt] = __builtin_amdgcn_mfma_f32_16x16x32_f16(Al, Bh, acc[nt], 0, 0, 0);
      acc[nt] = __builtin_amdgcn_mfma_f32_16x16x32_f16(Ah, Bl, acc[nt], 0, 0, 0);
    }
  }

  // C layout: lane(q,m) -> rows rowbase+q*4+r, col d = nt*16+m.
#pragma unroll
  for (int nt = 0; nt < 2; ++nt) {
    int d = nt * 16 + m;
    half4v h4;
#pragma unroll
    for (int r = 0; r < 4; ++r) h4[r] = (_Float16)acc[nt][r];
    *(half4v*)(whT + (size_t)(bh * Dd + d) * Nn + rowbase + q * 4) = h4;
  }

  const float* ah = a + h * 2 * Dd;
  float a1m0 = ah[m], a1m1 = ah[16 + m];
  float a2m0 = ah[Dd + m], a2m1 = ah[Dd + 16 + m];
#pragma unroll
  for (int r = 0; r < 4; ++r) {
    float ps = acc[0][r] * a1m0 + acc[1][r] * a1m1;
    float pt = acc[0][r] * a2m0 + acc[1][r] * a2m1;
#pragma unroll
    for (int off = 1; off < 16; off <<= 1) {
      ps += __shfl_xor(ps, off);
      pt += __shfl_xor(pt, off);
    }
    if (m == 0) {
      sArr[bh * Nn + rowbase + q * 4 + r] = ps;
      tArr[bh * Nn + rowbase + q * 4 + r] = pt;
    }
  }
}

// ---------------- Kernel 3: h = softmax(e) @ Wh via f16 MFMA ----------------
// 512 blocks (16 bh x 32 tiles of 64 rows) x 256 thr = 4 waves (j-quarters).
// Prologue: T = max t (block-reduce), E/F f16 tables in LDS, alpha/beta per row.
// Main loop (no barriers, no exp): P_pair = pk_max(aa*E2, bb*F2); den via fdot2.
__global__ __launch_bounds__(256) void k3_attn(
    const _Float16* __restrict__ whT, const float* __restrict__ sArr,
    const float* __restrict__ tArr, float* __restrict__ out) {
  __shared__ float smem[4 * 64 * 33 + 256];  // 34.8 KB union
  _Float16* Ef = (_Float16*)smem;            // [2048] f16 (1024 f32 slots)
  _Float16* Ff = (_Float16*)(smem + 1024);   // [2048] f16
  float* red = smem + 2048;                  // [256] block-max scratch

  int blk = blockIdx.x;
  int bh = blk >> 5, tile = blk & 31;
  int b = bh >> 2, h = bh & 3;
  int tid = threadIdx.x, w = tid >> 6, lane = tid & 63;
  int q = lane >> 4, m = lane & 15;

  // ---- prologue: T, then E_j = 2^(L(t-T)), F_j = 2^(0.2L(t-T)) ----
  float tv[8];
  float mx = -1e30f;
#pragma unroll
  for (int k = 0; k < 8; ++k) {
    tv[k] = tArr[bh * Nn + tid + k * 256];
    mx = fmaxf(mx, tv[k]);
  }
  red[tid] = mx;
  __syncthreads();
  for (int ss = 128; ss > 0; ss >>= 1) {
    if (tid < ss) red[tid] = fmaxf(red[tid], red[tid + ss]);
    __syncthreads();
  }
  float T = red[0];
  __syncthreads();
#pragma unroll
  for (int k = 0; k < 8; ++k) {
    float dt = tv[k] - T;                    // <= 0
    Ef[tid + k * 256] = (_Float16)__builtin_amdgcn_exp2f(LOG2E * dt);
    Ff[tid + k * 256] = (_Float16)__builtin_amdgcn_exp2f(0.2f * LOG2E * dt);
  }

  // per-row alpha/beta (replicated f16 pairs)
  half2v aa[4], bb[4];
#pragma unroll
  for (int t = 0; t < 4; ++t) {
    float es = sArr[bh * Nn + tile * 64 + t * 16 + m] + T;
    float al = __builtin_amdgcn_exp2f(0.8f * LOG2E * fminf(es, 0.f));
    float be = __builtin_amdgcn_exp2f(-0.8f * LOG2E * fmaxf(es, 0.f));
    _Float16 ah_ = (_Float16)al, bh_ = (_Float16)be;
    aa[t] = (half2v){ah_, ah_};
    bb[t] = (half2v){bh_, bh_};
  }
  __syncthreads();                           // E/F visible to all waves

  f32x4 acc[4][2];
#pragma unroll
  for (int t = 0; t < 4; ++t) {
    acc[t][0] = (f32x4){0.f, 0.f, 0.f, 0.f};
    acc[t][1] = (f32x4){0.f, 0.f, 0.f, 0.f};
  }
  float den[4] = {0.f, 0.f, 0.f, 0.f};
  const half2v ones = (half2v){(_Float16)1.f, (_Float16)1.f};

  const _Float16* wb = whT + (size_t)bh * Dd * Nn;

  // ---- main loop: 16 steps of 32 j, no barriers, no exp ----
  for (int s = 0; s < 16; ++s) {
    int jb = w * 512 + s * 32;
    half8 B0 = *(const half8*)(wb + (size_t)m * Nn + jb + q * 8);
    half8 B1 = *(const half8*)(wb + (size_t)(16 + m) * Nn + jb + q * 8);
    H8 E, F;
    E.h8 = *(const half8*)&Ef[jb + q * 8];   // LDS b128, quad-broadcast
    F.h8 = *(const half8*)&Ff[jb + q * 8];

#pragma unroll
    for (int t = 0; t < 4; ++t) {
      H8 P;
#pragma unroll
      for (int kk = 0; kk < 4; ++kk) {
        half2v pe = aa[t] * E.h2[kk];                        // v_pk_mul_f16
        half2v pf = bb[t] * F.h2[kk];                        // v_pk_mul_f16
        half2v p2 = __builtin_elementwise_max(pe, pf);       // v_pk_max_f16
        P.h2[kk] = p2;
        den[t] = __builtin_amdgcn_fdot2(p2, ones, den[t], false);
      }
      acc[t][0] = __builtin_amdgcn_mfma_f32_16x16x32_f16(P.h8, B0, acc[t][0], 0, 0, 0);
      acc[t][1] = __builtin_amdgcn_mfma_f32_16x16x32_f16(P.h8, B1, acc[t][1], 0, 0, 0);
    }
  }

  // ---- epilogue: cross-wave reduce + divide + elu + store ----
#pragma unroll
  for (int t = 0; t < 4; ++t) {
    den[t] += __shfl_xor(den[t], 16);
    den[t] += __shfl_xor(den[t], 32);
  }
  __syncthreads();                           // E/F dead; reuse smem
  float* redN = smem;                        // [4][64][33]
  float* redD = smem + 4 * 64 * 33;          // [4][64]
#pragma unroll
  for (int t = 0; t < 4; ++t) {
#pragma unroll
    for (int dh = 0; dh < 2; ++dh)
#pragma unroll
      for (int r = 0; r < 4; ++r)
        redN[(w * 64 + t * 16 + q * 4 + r) * 33 + dh * 16 + m] = acc[t][dh][r];
    if (q == 0) redD[w * 64 + t * 16 + m] = den[t];
  }
  __syncthreads();
  {
    int rl = tid >> 2, dg = (tid & 3) * 8;
    float num[8];
#pragma unroll
    for (int i = 0; i < 8; ++i)
      num[i] = redN[(0 * 64 + rl) * 33 + dg + i] + redN[(1 * 64 + rl) * 33 + dg + i] +
               redN[(2 * 64 + rl) * 33 + dg + i] + redN[(3 * 64 + rl) * 33 + dg + i];
    float dt = redD[rl] + redD[64 + rl] + redD[128 + rl] + redD[192 + rl];
    float rd = 1.0f / dt;                    // den >= ~1 by construction
    float* orow = out + (size_t)(b * Nn + tile * 64 + rl) * (4 * Dd) + h * Dd + dg;
#pragma unroll
    for (int i = 0; i < 8; ++i) {
      float hv = num[i] * rd;
      num[i] = hv > 0.f ? hv : (__builtin_amdgcn_exp2f(hv * LOG2E) - 1.0f);
    }
    *(float4*)orow = make_float4(num[0], num[1], num[2], num[3]);
    *((float4*)orow + 1) = make_float4(num[4], num[5], num[6], num[7]);
  }
}

extern "C" void kernel_launch(void* const* d_in, const int* in_sizes, int n_in,
                              void* d_out, int out_size, void* d_ws, size_t ws_size,
                              hipStream_t stream) {
  const float* x = (const float*)d_in[0];   // (4,2048,128)
  const float* W = (const float*)d_in[1];   // (4,128,32)
  const float* a = (const float*)d_in[2];   // (4,64)
  float* out = (float*)d_out;               // (4,2048,128)

  float* wsf = (float*)d_ws;
  float* sArr = wsf;                        // 32768 f32
  float* tArr = sArr + 32768;               // 32768 f32
  _Float16* whT = (_Float16*)(tArr + 32768);  // 16*32*2048 f16 = 2 MB

  k1_wh<<<dim3(512), dim3(256), 0, stream>>>(x, W, a, whT, sArr, tArr);
  k3_attn<<<dim3(512), dim3(256), 0, stream>>>(whT, sArr, tArr, out);
}